// Round 16
// baseline (309.342 us; speedup 1.0000x reference)
//
#include <hip/hip_runtime.h>
#include <hip/hip_bf16.h>
#include <cmath>

typedef __bf16 bf16;
typedef __bf16 bf16x4 __attribute__((ext_vector_type(4)));
typedef __bf16 bf16x8 __attribute__((ext_vector_type(8)));
typedef float f32x4 __attribute__((ext_vector_type(4)));

#define BB 4
#define CC 512
#define NN 4096      // 64*64 spatial
#define NRR 1024     // 32*32 spatial (stride-2)
#define NHH 8
#define DKK 64

static __device__ __forceinline__ bf16x8 ld8(const bf16* p) {
    return *reinterpret_cast<const bf16x8*>(p);
}

// swizzled index: element (row, col) of a [rows x 64] stripe.
static __device__ __forceinline__ int swz(int row, int col) {
    return row * 64 + ((((col >> 3) ^ (row & 7)) << 3) | (col & 7));
}

// ---------------------------------------------------------------------------
// fused prep (layout A): blocks [0,4096) do weight permute/convert + stats
// zero; blocks [4096, 6144) do the x transpose.
// Wq is pre-scaled by 0.125*log2(e) so QK^T lands directly in exp2 domain.
// ---------------------------------------------------------------------------
static __device__ __forceinline__ void wprep_body(int e,
                                                  const float* __restrict__ Wq,
                                                  const float* __restrict__ Wp,
                                                  const float* __restrict__ Wk,
                                                  const float* __restrict__ Wv,
                                                  bf16* __restrict__ Wqb,
                                                  bf16* __restrict__ Wpb,
                                                  bf16* __restrict__ Wkf,
                                                  bf16* __restrict__ Wvf,
                                                  float* __restrict__ stats) {
    int o = e >> 11, q = (e >> 9) & 3, ci = e & 511;
    int src = o * 2048 + ci * 4 + q;
    Wkf[e] = (bf16)Wk[src];
    Wvf[e] = (bf16)Wv[src];
    if (e < 262144) {
        Wqb[e] = (bf16)(Wq[e] * 0.18033688011f);  // 0.125 * log2(e)
        Wpb[e] = (bf16)Wp[e];
    }
    if (e < 1024) stats[e] = 0.f;
}

__global__ __launch_bounds__(256) void prep_kernel(const float* __restrict__ Wq,
                                                   const float* __restrict__ Wp,
                                                   const float* __restrict__ Wk,
                                                   const float* __restrict__ Wv,
                                                   bf16* __restrict__ Wqb,
                                                   bf16* __restrict__ Wpb,
                                                   bf16* __restrict__ Wkf,
                                                   bf16* __restrict__ Wvf,
                                                   float* __restrict__ stats,
                                                   const float* __restrict__ x,
                                                   bf16* __restrict__ xt) {
    __shared__ bf16 tile[64][65];
    if (blockIdx.x < 4096) {
        int e = blockIdx.x * 256 + threadIdx.x;
        wprep_body(e, Wq, Wp, Wk, Wv, Wqb, Wpb, Wkf, Wvf, stats);
        return;
    }
    int bid = blockIdx.x - 4096;             // 2048 transpose blocks
    int b = bid >> 9;
    int by = (bid >> 6) & 7, bx = bid & 63;
    const float* xb = x + (size_t)b * CC * NN;
    bf16* xtb = xt + (size_t)b * NN * CC;
    int n0 = bx * 64, c0 = by * 64;
    int tr = threadIdx.x >> 6, tc = threadIdx.x & 63;
#pragma unroll
    for (int i = 0; i < 64; i += 4)
        tile[tc][i + tr] = (bf16)xb[(long)(c0 + i + tr) * NN + n0 + tc];
    __syncthreads();
#pragma unroll
    for (int i = 0; i < 64; i += 4)
        xtb[(long)(n0 + i + tr) * CC + c0 + tc] = tile[i + tr][tc];
}

// standalone versions for layout B (per-batch loop)
__global__ __launch_bounds__(256) void wprep_kernel(const float* __restrict__ Wq,
                                                    const float* __restrict__ Wp,
                                                    const float* __restrict__ Wk,
                                                    const float* __restrict__ Wv,
                                                    bf16* __restrict__ Wqb,
                                                    bf16* __restrict__ Wpb,
                                                    bf16* __restrict__ Wkf,
                                                    bf16* __restrict__ Wvf,
                                                    float* __restrict__ stats) {
    int e = blockIdx.x * 256 + threadIdx.x;
    wprep_body(e, Wq, Wp, Wk, Wv, Wqb, Wpb, Wkf, Wvf, stats);
}

__global__ __launch_bounds__(256) void transpose_kernel(const float* __restrict__ x,
                                                        bf16* __restrict__ xt) {
    __shared__ bf16 tile[64][65];
    int b = blockIdx.z;
    const float* xb = x + (size_t)b * CC * NN;
    bf16* xtb = xt + (size_t)b * NN * CC;
    int n0 = blockIdx.x * 64, c0 = blockIdx.y * 64;
    int tr = threadIdx.x >> 6, tc = threadIdx.x & 63;
#pragma unroll
    for (int i = 0; i < 64; i += 4)
        tile[tc][i + tr] = (bf16)xb[(long)(c0 + i + tr) * NN + n0 + tc];
    __syncthreads();
#pragma unroll
    for (int i = 0; i < 64; i += 4)
        xtb[(long)(n0 + i + tr) * CC + c0 + tc] = tile[i + tr][tc];
}

// ---------------------------------------------------------------------------
// Merged K+V GEMM, BK=64, 2-deep software pipeline: weight-staging and
// im2col A-gather loads issued TWO tiles ahead (in flight ~1.5 steps =
// 300+ cyc, covering L2 latency). Unrolled 2x -> static dbuf indices.
// ---------------------------------------------------------------------------
__global__ __launch_bounds__(256) void gemm_kv(const bf16* __restrict__ xt,
                                               const bf16* __restrict__ Wkf,
                                               const bf16* __restrict__ Wvf,
                                               bf16* __restrict__ kt,
                                               bf16* __restrict__ vt) {
    __shared__ __align__(16) bf16 smem[2][2][64][72];   // [dbuf][K/V][ch][k]
    const f32x4 fzero = {0.f, 0.f, 0.f, 0.f};
    int b = blockIdx.z;
    const bf16* xtb = xt + (size_t)b * NN * CC;
    int w = threadIdx.x >> 6, lane = threadIdx.x & 63;
    int quad = lane >> 4, l15 = lane & 15;
    int m0 = blockIdx.x * 64 + w * 16;
    int n0 = blockIdx.y * 64;

    int m = m0 + l15;
    int i2 = m >> 5, j2 = m & 31;
    int nrow[4];
#pragma unroll
    for (int q = 0; q < 4; ++q)
        nrow[q] = (2 * i2 + (q >> 1)) * 64 + 2 * j2 + (q & 1);

    int srow = threadIdx.x >> 2, sseg = threadIdx.x & 3;
    const bf16* wkp = Wkf + (long)(n0 + srow) * 2048 + sseg * 8;
    const bf16* wvp = Wvf + (long)(n0 + srow) * 2048 + sseg * 8;

    // prologue: stage tile 0 direct; hold tile 1 in regs; A for tiles 0,1
    {
        *reinterpret_cast<bf16x8*>(&smem[0][0][srow][sseg * 8]) = ld8(wkp);
        *reinterpret_cast<bf16x8*>(&smem[0][0][srow][32 + sseg * 8]) = ld8(wkp + 32);
        *reinterpret_cast<bf16x8*>(&smem[0][1][srow][sseg * 8]) = ld8(wvp);
        *reinterpret_cast<bf16x8*>(&smem[0][1][srow][32 + sseg * 8]) = ld8(wvp + 32);
    }
    bf16x8 svK0a = ld8(wkp + 64), svK1a = ld8(wkp + 96);
    bf16x8 svV0a = ld8(wvp + 64), svV1a = ld8(wvp + 96);
    bf16x8 aA0 = ld8(xtb + (long)nrow[0] * CC + quad * 8);
    bf16x8 aA1 = ld8(xtb + (long)nrow[0] * CC + 32 + quad * 8);
    bf16x8 aB0 = ld8(xtb + (long)nrow[0] * CC + 64 + quad * 8);
    bf16x8 aB1 = ld8(xtb + (long)nrow[0] * CC + 96 + quad * 8);
    __syncthreads();

    f32x4 accK[4], accV[4];
#pragma unroll
    for (int ct = 0; ct < 4; ++ct) { accK[ct] = fzero; accV[ct] = fzero; }

    bf16x8 svK0b, svK1b, svV0b, svV1b;
    for (int kp = 0; kp < 16; ++kp) {
        int s = 2 * kp;
        // ---- even step s: compute from smem[0] with aA
#pragma unroll
        for (int ct = 0; ct < 4; ++ct) {
            bf16x8 bk0 = ld8(&smem[0][0][ct * 16 + l15][quad * 8]);
            bf16x8 bv0 = ld8(&smem[0][1][ct * 16 + l15][quad * 8]);
            accK[ct] = __builtin_amdgcn_mfma_f32_16x16x32_bf16(aA0, bk0, accK[ct], 0, 0, 0);
            accV[ct] = __builtin_amdgcn_mfma_f32_16x16x32_bf16(aA0, bv0, accV[ct], 0, 0, 0);
            bf16x8 bk1 = ld8(&smem[0][0][ct * 16 + l15][32 + quad * 8]);
            bf16x8 bv1 = ld8(&smem[0][1][ct * 16 + l15][32 + quad * 8]);
            accK[ct] = __builtin_amdgcn_mfma_f32_16x16x32_bf16(aA1, bk1, accK[ct], 0, 0, 0);
            accV[ct] = __builtin_amdgcn_mfma_f32_16x16x32_bf16(aA1, bv1, accV[ct], 0, 0, 0);
        }
        // write held tile s+1 into smem[1]
        *reinterpret_cast<bf16x8*>(&smem[1][0][srow][sseg * 8]) = svK0a;
        *reinterpret_cast<bf16x8*>(&smem[1][0][srow][32 + sseg * 8]) = svK1a;
        *reinterpret_cast<bf16x8*>(&smem[1][1][srow][sseg * 8]) = svV0a;
        *reinterpret_cast<bf16x8*>(&smem[1][1][srow][32 + sseg * 8]) = svV1a;
        if (kp < 15) {
            int k2 = (s + 2) * 64;
            svK0b = ld8(wkp + k2); svK1b = ld8(wkp + k2 + 32);
            svV0b = ld8(wvp + k2); svV1b = ld8(wvp + k2 + 32);
            int q2 = k2 >> 9, ci2 = k2 & 511;
            aA0 = ld8(xtb + (long)nrow[q2] * CC + ci2 + quad * 8);
            aA1 = ld8(xtb + (long)nrow[q2] * CC + ci2 + 32 + quad * 8);
        }
        __syncthreads();
        // ---- odd step s+1: compute from smem[1] with aB
#pragma unroll
        for (int ct = 0; ct < 4; ++ct) {
            bf16x8 bk0 = ld8(&smem[1][0][ct * 16 + l15][quad * 8]);
            bf16x8 bv0 = ld8(&smem[1][1][ct * 16 + l15][quad * 8]);
            accK[ct] = __builtin_amdgcn_mfma_f32_16x16x32_bf16(aB0, bk0, accK[ct], 0, 0, 0);
            accV[ct] = __builtin_amdgcn_mfma_f32_16x16x32_bf16(aB0, bv0, accV[ct], 0, 0, 0);
            bf16x8 bk1 = ld8(&smem[1][0][ct * 16 + l15][32 + quad * 8]);
            bf16x8 bv1 = ld8(&smem[1][1][ct * 16 + l15][32 + quad * 8]);
            accK[ct] = __builtin_amdgcn_mfma_f32_16x16x32_bf16(aB1, bk1, accK[ct], 0, 0, 0);
            accV[ct] = __builtin_amdgcn_mfma_f32_16x16x32_bf16(aB1, bv1, accV[ct], 0, 0, 0);
        }
        if (kp < 15) {
            // write tile s+2 into smem[0]; load tile s+3 + its A
            *reinterpret_cast<bf16x8*>(&smem[0][0][srow][sseg * 8]) = svK0b;
            *reinterpret_cast<bf16x8*>(&smem[0][0][srow][32 + sseg * 8]) = svK1b;
            *reinterpret_cast<bf16x8*>(&smem[0][1][srow][sseg * 8]) = svV0b;
            *reinterpret_cast<bf16x8*>(&smem[0][1][srow][32 + sseg * 8]) = svV1b;
            int k3 = (s + 3) * 64;
            svK0a = ld8(wkp + k3); svK1a = ld8(wkp + k3 + 32);
            svV0a = ld8(wvp + k3); svV1a = ld8(wvp + k3 + 32);
            int q3 = k3 >> 9, ci3 = k3 & 511;
            aB0 = ld8(xtb + (long)nrow[q3] * CC + ci3 + quad * 8);
            aB1 = ld8(xtb + (long)nrow[q3] * CC + ci3 + 32 + quad * 8);
        }
        __syncthreads();
    }

    bf16* Ck = kt + (size_t)b * NRR * CC;
#pragma unroll
    for (int ct = 0; ct < 4; ++ct)
#pragma unroll
        for (int r = 0; r < 4; ++r)
            Ck[(long)(m0 + quad * 4 + r) * CC + n0 + ct * 16 + l15] = (bf16)accK[ct][r];

    bf16* tt = (bf16*)smem;   // viewed as [64][72]
#pragma unroll
    for (int ct = 0; ct < 4; ++ct)
#pragma unroll
        for (int r = 0; r < 4; ++r)
            tt[(ct * 16 + l15) * 72 + w * 16 + quad * 4 + r] = (bf16)accV[ct][r];
    __syncthreads();
    {
        int row = threadIdx.x >> 2, seg = threadIdx.x & 3;
        bf16x8 v0 = ld8(tt + row * 72 + seg * 16);
        bf16x8 v1 = ld8(tt + row * 72 + seg * 16 + 8);
        bf16* dst = vt + (size_t)b * CC * NRR + (long)(n0 + row) * NRR
                  + (long)blockIdx.x * 64 + seg * 16;
        *reinterpret_cast<bf16x8*>(dst) = v0;
        *reinterpret_cast<bf16x8*>(dst + 8) = v1;
    }
}

// ---------------------------------------------------------------------------
// flash attention, swapped-operand QK^T, FOUR query tiles per wave (64 q).
// m == 0 exact softmax (logits |s| <~ 20 in log2 domain). 2-phase main loop:
// kfA/kfB K-fragment sets alternate (no register copies; static vbuf index).
// ---------------------------------------------------------------------------
#define VST 64   // vbuf row stride (bf16 elements)
#define QT 4     // query tiles per wave
__global__ __launch_bounds__(256) void attn_kernel(const bf16* __restrict__ xt,
                                                   const bf16* __restrict__ Wqb,
                                                   const bf16* __restrict__ Kt,
                                                   const bf16* __restrict__ Vt,
                                                   const float* __restrict__ bias,
                                                   bf16* __restrict__ Ot) {
    __shared__ __align__(16) bf16 vbuf[2][64 * VST];    // [d][m] XOR-swizzled
    __shared__ __align__(16) bf16 ptile[4][64 * 64];    // per-wave swz stripes
    const f32x4 fzero = {0.f, 0.f, 0.f, 0.f};
    (void)bias;                                         // softmax-invariant
    int b = blockIdx.z, h = blockIdx.y;
    const bf16* xtb = xt + (size_t)b * NN * CC;
    const bf16* Ktb = Kt + (size_t)b * NRR * CC;
    const bf16* Vtb = Vt + (size_t)b * CC * NRR;        // [c][m] layout
    bf16* Otb = Ot + (size_t)b * NN * CC;
    int w = threadIdx.x >> 6, lane = threadIdx.x & 63;
    int quad = lane >> 4, l15 = lane & 15;
    int m0 = blockIdx.x * 256 + w * 64;                 // tiles at m0 + t*16

    // staging geometry: thread covers (d0, chunk) and (d0+32, chunk)
    int sd0 = threadIdx.x >> 3, schunk = threadIdx.x & 7;
    const bf16* vsrc0 = Vtb + (long)(h * DKK + sd0) * NRR + schunk * 8;
    const bf16* vsrc1 = vsrc0 + (long)32 * NRR;
    int soff0 = sd0 * VST + ((schunk ^ (sd0 & 7)) * 8);
    int soff1 = (sd0 + 32) * VST + ((schunk ^ (sd0 & 7)) * 8);

    // fused Q-GEMM for 4 tiles (Wq fragments shared)
    bf16* ql = &ptile[w][0];
    {
        f32x4 qacc[QT][4];
#pragma unroll
        for (int t = 0; t < QT; ++t)
#pragma unroll
            for (int ct = 0; ct < 4; ++ct) qacc[t][ct] = fzero;
        const bf16* axp = xtb + (long)(m0 + l15) * CC + quad * 8;
        const bf16* bwp = Wqb + (long)(h * DKK + l15) * CC + quad * 8;
        for (int k0 = 0; k0 < 512; k0 += 32) {
            bf16x8 av[QT];
#pragma unroll
            for (int t = 0; t < QT; ++t) av[t] = ld8(axp + t * 16 * CC + k0);
#pragma unroll
            for (int ct = 0; ct < 4; ++ct) {
                bf16x8 bv = ld8(bwp + k0 + ct * 16 * CC);
#pragma unroll
                for (int t = 0; t < QT; ++t)
                    qacc[t][ct] = __builtin_amdgcn_mfma_f32_16x16x32_bf16(av[t], bv, qacc[t][ct], 0, 0, 0);
            }
        }
#pragma unroll
        for (int t = 0; t < QT; ++t)
#pragma unroll
            for (int ct = 0; ct < 4; ++ct)
#pragma unroll
                for (int r = 0; r < 4; ++r)
                    ql[swz(t * 16 + quad * 4 + r, ct * 16 + l15)] = (bf16)qacc[t][ct][r];
    }
    asm volatile("s_waitcnt lgkmcnt(0)" ::: "memory");
    __builtin_amdgcn_sched_barrier(0);
    bf16x8 aq0[QT], aq1[QT];
#pragma unroll
    for (int t = 0; t < QT; ++t) {
        aq0[t] = ld8(ql + swz(t * 16 + l15, quad * 8));
        aq1[t] = ld8(ql + swz(t * 16 + l15, 32 + quad * 8));
    }

    // prologue: stage V tile 0; preload K fragments for tile 0 into set A
    {
        bf16x8 s0 = ld8(vsrc0);
        bf16x8 s1 = ld8(vsrc1);
        *reinterpret_cast<bf16x8*>(&vbuf[0][0] + soff0) = s0;
        *reinterpret_cast<bf16x8*>(&vbuf[0][0] + soff1) = s1;
    }
    const bf16* kbase = Ktb + (long)l15 * CC + h * DKK + quad * 8;
    bf16x8 kfA0[4], kfA1[4], kfB0[4], kfB1[4];
#pragma unroll
    for (int ct = 0; ct < 4; ++ct) {
        kfA0[ct] = ld8(kbase + (long)ct * 16 * CC);
        kfA1[ct] = ld8(kbase + (long)ct * 16 * CC + 32);
    }
    __syncthreads();

    f32x4 oacc[QT][4];
    float lrow[QT];
#pragma unroll
    for (int t = 0; t < QT; ++t) {
        lrow[t] = 0.f;
#pragma unroll
        for (int ct = 0; ct < 4; ++ct) oacc[t][ct] = fzero;
    }

    auto attn_step = [&](int kt, int cur, bf16x8 (&ku0)[4], bf16x8 (&ku1)[4],
                         bf16x8 (&kn0)[4], bf16x8 (&kn1)[4]) {
        bf16x8 sv0, sv1;
        if (kt < 15) {
            sv0 = ld8(vsrc0 + (kt + 1) * 64);
            sv1 = ld8(vsrc1 + (kt + 1) * 64);
        }
        bf16* pl = &ptile[w][0];
#pragma unroll
        for (int t = 0; t < QT; ++t) {
            f32x4 s[4];
#pragma unroll
            for (int ct = 0; ct < 4; ++ct) s[ct] = fzero;
            __builtin_amdgcn_s_setprio(1);
#pragma unroll
            for (int ct = 0; ct < 4; ++ct) {
                s[ct] = __builtin_amdgcn_mfma_f32_16x16x32_bf16(ku0[ct], aq0[t], s[ct], 0, 0, 0);
                s[ct] = __builtin_amdgcn_mfma_f32_16x16x32_bf16(ku1[ct], aq1[t], s[ct], 0, 0, 0);
            }
            __builtin_amdgcn_s_setprio(0);
            float ls = 0.f;
#pragma unroll
            for (int ct = 0; ct < 4; ++ct) {
                bf16x4 pk;
#pragma unroll
                for (int r = 0; r < 4; ++r) {
                    float e = __builtin_amdgcn_exp2f(s[ct][r]);
                    ls += e;
                    pk[r] = (bf16)e;
                }
                *reinterpret_cast<bf16x4*>(pl + swz(t * 16 + l15, ct * 16 + quad * 4)) = pk;
            }
            lrow[t] += ls;
        }
        asm volatile("s_waitcnt lgkmcnt(0)" ::: "memory");
        __builtin_amdgcn_sched_barrier(0);

        // issue next-tile K loads into the OTHER fragment set (no copies)
        if (kt < 15) {
            const bf16* kn = kbase + (long)(kt + 1) * 64 * CC;
#pragma unroll
            for (int ct = 0; ct < 4; ++ct) {
                kn0[ct] = ld8(kn + (long)ct * 16 * CC);
                kn1[ct] = ld8(kn + (long)ct * 16 * CC + 32);
            }
        }

        // O^T += V^T P^T  (V fragments shared across 4 tiles)
        const bf16* vb = &vbuf[cur][0];
        __builtin_amdgcn_s_setprio(1);
#pragma unroll
        for (int ks = 0; ks < 2; ++ks) {
            bf16x8 bp[QT];
#pragma unroll
            for (int t = 0; t < QT; ++t)
                bp[t] = ld8(pl + swz(t * 16 + l15, ks * 32 + quad * 8));
#pragma unroll
            for (int ct = 0; ct < 4; ++ct) {
                int d = ct * 16 + l15;
                bf16x8 av = ld8(vb + d * VST + (((ks * 4 + quad) ^ (d & 7)) * 8));
#pragma unroll
                for (int t = 0; t < QT; ++t)
                    oacc[t][ct] = __builtin_amdgcn_mfma_f32_16x16x32_bf16(av, bp[t], oacc[t][ct], 0, 0, 0);
            }
        }
        __builtin_amdgcn_s_setprio(0);

        if (kt < 15) {
            bf16* wb = &vbuf[cur ^ 1][0];
            *reinterpret_cast<bf16x8*>(wb + soff0) = sv0;
            *reinterpret_cast<bf16x8*>(wb + soff1) = sv1;
        }
        __syncthreads();
    };

    for (int kp = 0; kp < 8; ++kp) {
        attn_step(2 * kp, 0, kfA0, kfA1, kfB0, kfB1);
        attn_step(2 * kp + 1, 1, kfB0, kfB1, kfA0, kfA1);
    }

    // final denominators + O epilogue per tile
    bf16* pl = &ptile[w][0];
#pragma unroll
    for (int t = 0; t < QT; ++t) {
        float lr = lrow[t];
        lr += __shfl_xor(lr, 16);
        lr += __shfl_xor(lr, 32);
        float inv = 1.f / lr;
#pragma unroll
        for (int ct = 0; ct < 4; ++ct) {
            bf16x4 ok;
#pragma unroll
            for (int r = 0; r < 4; ++r) ok[r] = (bf16)(oacc[t][ct][r] * inv);
            *reinterpret_cast<bf16x4*>(pl + swz(t * 16 + l15, ct * 16 + quad * 4)) = ok;
        }
    }
    asm volatile("s_waitcnt lgkmcnt(0)" ::: "memory");
    __builtin_amdgcn_sched_barrier(0);
#pragma unroll
    for (int t = 0; t < QT; ++t) {
        bf16x8 o0 = ld8(pl + swz(t * 16 + l15, quad * 16));
        bf16x8 o1 = ld8(pl + swz(t * 16 + l15, quad * 16 + 8));
        bf16* dst = Otb + (long)(m0 + t * 16 + l15) * CC + h * DKK + quad * 16;
        *reinterpret_cast<bf16x8*>(dst) = o0;
        *reinterpret_cast<bf16x8*>(dst + 8) = o1;
    }
}

// ---------------------------------------------------------------------------
// proj: p[b,o,n] = Wproj . ot[b,n,:]^T, fp32 out; LDS-staged GEMM, BK=64,
// 2-deep pipeline (staging loads issued two tiles ahead). BN stats fused.
// ---------------------------------------------------------------------------
__global__ __launch_bounds__(256) void gemm_ntf(const bf16* __restrict__ A,
                                                const bf16* __restrict__ Bt,
                                                float* __restrict__ C,
                                                float* __restrict__ stats) {
    __shared__ __align__(16) bf16 sa[2][64][72];   // Wpb tile [ch][k]
    __shared__ __align__(16) bf16 sb[2][64][72];   // ot tile [px][k]
    const f32x4 fzero = {0.f, 0.f, 0.f, 0.f};
    int b = blockIdx.z;
    const bf16* Btb = Bt + (size_t)b * NN * CC;
    float* Cb = C + (size_t)b * CC * NN;
    int w = threadIdx.x >> 6, lane = threadIdx.x & 63;
    int quad = lane >> 4, l15 = lane & 15;
    long m0 = (long)blockIdx.x * 64 + w * 16;
    long n0 = (long)blockIdx.y * 64;

    int srow = threadIdx.x >> 2, sseg = threadIdx.x & 3;
    const bf16* apS = A + ((long)blockIdx.x * 64 + srow) * CC + sseg * 8;
    const bf16* bpS = Btb + (n0 + srow) * CC + sseg * 8;

    // prologue: tile 0 direct; tile 1 held in set A
    {
        *reinterpret_cast<bf16x8*>(&sa[0][srow][sseg * 8]) = ld8(apS);
        *reinterpret_cast<bf16x8*>(&sa[0][srow][32 + sseg * 8]) = ld8(apS + 32);
        *reinterpret_cast<bf16x8*>(&sb[0][srow][sseg * 8]) = ld8(bpS);
        *reinterpret_cast<bf16x8*>(&sb[0][srow][32 + sseg * 8]) = ld8(bpS + 32);
    }
    bf16x8 svA0a = ld8(apS + 64), svA1a = ld8(apS + 96);
    bf16x8 svB0a = ld8(bpS + 64), svB1a = ld8(bpS + 96);
    __syncthreads();

    f32x4 acc[4];
#pragma unroll
    for (int ct = 0; ct < 4; ++ct) acc[ct] = fzero;

    bf16x8 svA0b, svA1b, svB0b, svB1b;
    for (int kp = 0; kp < 4; ++kp) {
        int s = 2 * kp;
        // even step: compute from [0]
        {
            bf16x8 a0 = ld8(&sa[0][w * 16 + l15][quad * 8]);
            bf16x8 a1 = ld8(&sa[0][w * 16 + l15][32 + quad * 8]);
#pragma unroll
            for (int ct = 0; ct < 4; ++ct) {
                bf16x8 b0 = ld8(&sb[0][ct * 16 + l15][quad * 8]);
                acc[ct] = __builtin_amdgcn_mfma_f32_16x16x32_bf16(a0, b0, acc[ct], 0, 0, 0);
                bf16x8 b1 = ld8(&sb[0][ct * 16 + l15][32 + quad * 8]);
                acc[ct] = __builtin_amdgcn_mfma_f32_16x16x32_bf16(a1, b1, acc[ct], 0, 0, 0);
            }
        }
        *reinterpret_cast<bf16x8*>(&sa[1][srow][sseg * 8]) = svA0a;
        *reinterpret_cast<bf16x8*>(&sa[1][srow][32 + sseg * 8]) = svA1a;
        *reinterpret_cast<bf16x8*>(&sb[1][srow][sseg * 8]) = svB0a;
        *reinterpret_cast<bf16x8*>(&sb[1][srow][32 + sseg * 8]) = svB1a;
        if (kp < 3) {
            int k2 = (s + 2) * 64;
            svA0b = ld8(apS + k2); svA1b = ld8(apS + k2 + 32);
            svB0b = ld8(bpS + k2); svB1b = ld8(bpS + k2 + 32);
        }
        __syncthreads();
        // odd step: compute from [1]
        {
            bf16x8 a0 = ld8(&sa[1][w * 16 + l15][quad * 8]);
            bf16x8 a1 = ld8(&sa[1][w * 16 + l15][32 + quad * 8]);
#pragma unroll
            for (int ct = 0; ct < 4; ++ct) {
                bf16x8 b0 = ld8(&sb[1][ct * 16 + l15][quad * 8]);
                acc[ct] = __builtin_amdgcn_mfma_f32_16x16x32_bf16(a0, b0, acc[ct], 0, 0, 0);
                bf16x8 b1 = ld8(&sb[1][ct * 16 + l15][32 + quad * 8]);
                acc[ct] = __builtin_amdgcn_mfma_f32_16x16x32_bf16(a1, b1, acc[ct], 0, 0, 0);
            }
        }
        if (kp < 3) {
            *reinterpret_cast<bf16x8*>(&sa[0][srow][sseg * 8]) = svA0b;
            *reinterpret_cast<bf16x8*>(&sa[0][srow][32 + sseg * 8]) = svA1b;
            *reinterpret_cast<bf16x8*>(&sb[0][srow][sseg * 8]) = svB0b;
            *reinterpret_cast<bf16x8*>(&sb[0][srow][32 + sseg * 8]) = svB1b;
            int k3 = (s + 3) * 64;
            svA0a = ld8(apS + k3); svA1a = ld8(apS + k3 + 32);
            svB0a = ld8(bpS + k3); svB1a = ld8(bpS + k3 + 32);
        }
        __syncthreads();
    }

    float ps[4], pss[4];
#pragma unroll
    for (int r = 0; r < 4; ++r) { ps[r] = 0.f; pss[r] = 0.f; }
#pragma unroll
    for (int ct = 0; ct < 4; ++ct)
#pragma unroll
        for (int r = 0; r < 4; ++r) {
            float v = acc[ct][r];
            Cb[(m0 + quad * 4 + r) * NN + n0 + ct * 16 + l15] = v;
            ps[r] += v; pss[r] += v * v;
        }
#pragma unroll
    for (int off = 1; off < 16; off <<= 1)
#pragma unroll
        for (int r = 0; r < 4; ++r) {
            ps[r] += __shfl_xor(ps[r], off);
            pss[r] += __shfl_xor(pss[r], off);
        }
    if (l15 == 0) {
#pragma unroll
        for (int r = 0; r < 4; ++r) {
            int c = (int)(m0 + quad * 4 + r);
            atomicAdd(&stats[c * 2], ps[r]);
            atomicAdd(&stats[c * 2 + 1], pss[r]);
        }
    }
}

// ---------------------------------------------------------------------------
// y = x + bn(p); LayerNorm over C per pixel. Single global read pass:
// y cached in LDS (512ch x 32px fp32 = 64 KB), second pass reads LDS only.
// ---------------------------------------------------------------------------
__global__ __launch_bounds__(256) void final_kernel(const float* __restrict__ x,
                                                    const float* __restrict__ p,
                                                    const float* __restrict__ stats,
                                                    const float* __restrict__ bng,
                                                    const float* __restrict__ bnb,
                                                    const float* __restrict__ lg,
                                                    const float* __restrict__ lb,
                                                    float* __restrict__ out) {
    __shared__ float yt[512 * 32];           // [c][px], stride 32 (2-way, free)
    __shared__ float scs[512], shs[512], lgs[512], lbs[512];
    __shared__ float rs[8][32], rss[8][32];
    for (int c = threadIdx.x; c < 512; c += 256) {
        float sum = stats[c * 2], ssq = stats[c * 2 + 1];
        float mean = sum * (1.f / 16384.f);
        float var = ssq * (1.f / 16384.f) - mean * mean;
        float rstd = rsqrtf(var + 1e-5f);
        float sc = bng[c] * rstd;
        scs[c] = sc;
        shs[c] = bnb[c] - mean * sc;
        lgs[c] = lg[c];
        lbs[c] = lb[c];
    }
    __syncthreads();
    int blk = blockIdx.x;
    int b = blk >> 7;                        // 128 pixel-groups per batch
    int pix0 = (blk & 127) * 32;
    int sub = threadIdx.x >> 5, px = threadIdx.x & 31;   // 8 subs x 32 px
    float s = 0.f, ss = 0.f;
    for (int i = 0; i < 64; ++i) {
        int c = i * 8 + sub;
        long idx = ((long)(b * CC + c)) * NN + pix0 + px;
        float y = x[idx] + p[idx] * scs[c] + shs[c];
        yt[c * 32 + px] = y;
        s += y; ss += y * y;
    }
    rs[sub][px] = s; rss[sub][px] = ss;
    __syncthreads();
    float sum = 0.f, sq = 0.f;
#pragma unroll
    for (int j = 0; j < 8; ++j) { sum += rs[j][px]; sq += rss[j][px]; }
    float mu = sum * (1.f / 512.f);
    float var = sq * (1.f / 512.f) - mu * mu;
    float rstd = rsqrtf(var + 1e-5f);
    for (int i = 0; i < 64; ++i) {
        int c = i * 8 + sub;
        long idx = ((long)(b * CC + c)) * NN + pix0 + px;
        out[idx] = (yt[c * 32 + px] - mu) * rstd * lgs[c] + lbs[c];
    }
}

// ---------------------------------------------------------------------------
extern "C" void kernel_launch(void* const* d_in, const int* in_sizes, int n_in,
                              void* d_out, int out_size, void* d_ws, size_t ws_size,
                              hipStream_t stream) {
    (void)in_sizes; (void)n_in; (void)out_size;
    const float* x     = (const float*)d_in[0];
    const float* Wq    = (const float*)d_in[1];
    const float* Wk    = (const float*)d_in[2];
    const float* Wv    = (const float*)d_in[3];
    const float* bias  = (const float*)d_in[4];
    const float* Wproj = (const float*)d_in[5];
    const float* bng   = (const float*)d_in[6];
    const float* bnb   = (const float*)d_in[7];
    const float* lng   = (const float*)d_in[8];
    const float* lnb   = (const float*)d_in[9];
    float* out = (float*)d_out;   // fp32 output (verified R9)

    char* ws = (char*)d_ws;
    size_t off = 0;
    auto alloc = [&](size_t bytes) {
        char* pp = ws + off;
        off += (bytes + 255) & ~(size_t)255;
        return pp;
    };
    bf16* Wqb = (bf16*)alloc((size_t)CC * CC * 2);          // 0.52 MB
    bf16* Wpb = (bf16*)alloc((size_t)CC * CC * 2);          // 0.52 MB
    float* stats = (float*)alloc(512 * 2 * sizeof(float));

    size_t needA = off + ((size_t)CC * 2048 * 2 * 2)        // Wkf+Wvf 4.2 MB
                 + ((size_t)BB * NN * CC * 2)               // xt_all 16.8
                 + ((size_t)BB * NRR * CC * 2 * 2)          // kt+vt   8.4
                 + ((size_t)BB * NN * CC * 2) + 4096;       // ot_all 16.8

    if (ws_size >= needA) {
        bf16* Wkf = (bf16*)alloc((size_t)CC * 2048 * 2);
        bf16* Wvf = (bf16*)alloc((size_t)CC * 2048 * 2);
        bf16* xt  = (bf16*)alloc((size_t)BB * NN * CC * 2);
        bf16* kt  = (bf16*)alloc((size_t)BB * NRR * CC * 2);
        bf16* vt  = (bf16*)alloc((size_t)BB * NRR * CC * 2);   // holds V^T [c][m]
        bf16* ot  = (bf16*)alloc((size_t)BB * NN * CC * 2);

        prep_kernel<<<4096 + 2048, 256, 0, stream>>>(Wq, Wproj, Wk, Wv, Wqb, Wpb,
                                                     Wkf, Wvf, stats, x, xt);
        gemm_kv<<<dim3(16, 8, BB), 256, 0, stream>>>(xt, Wkf, Wvf, kt, vt);
        attn_kernel<<<dim3(16, NHH, BB), 256, 0, stream>>>(xt, Wqb, kt, vt, bias, ot);
        gemm_ntf<<<dim3(8, 64, BB), 256, 0, stream>>>(Wpb, ot, out, stats);
    } else {
        bf16* Wkf = (bf16*)(out + (size_t)3 * CC * NN);
        bf16* Wvf = Wkf + (size_t)CC * 2048;
        bf16* xt = (bf16*)alloc((size_t)NN * CC * 2);
        bf16* kt = (bf16*)alloc((size_t)NRR * CC * 2);
        bf16* vt = (bf16*)alloc((size_t)NRR * CC * 2);         // V^T [c][m]
        bf16* ot = (bf16*)alloc((size_t)NN * CC * 2);

        wprep_kernel<<<4096, 256, 0, stream>>>(Wq, Wproj, Wk, Wv, Wqb, Wpb, Wkf, Wvf, stats);
        for (int b = 0; b < BB; ++b) {
            const float* xb = x + (size_t)b * CC * NN;
            float* pb = out + (size_t)b * CC * NN;
            transpose_kernel<<<dim3(64, 8, 1), 256, 0, stream>>>(xb, xt);
            gemm_kv<<<dim3(16, 8, 1), 256, 0, stream>>>(xt, Wkf, Wvf, kt, vt);
            attn_kernel<<<dim3(16, NHH, 1), 256, 0, stream>>>(xt, Wqb, kt, vt, bias, ot);
            gemm_ntf<<<dim3(8, 64, 1), 256, 0, stream>>>(Wpb, ot, pb, stats);
        }
    }

    final_kernel<<<512, 256, 0, stream>>>(x, out, stats, bng, bnb, lng, lnb, out);
}

// Round 17
// 284.080 us; speedup vs baseline: 1.0889x; 1.0889x over previous
//
#include <hip/hip_runtime.h>
#include <hip/hip_bf16.h>
#include <cmath>

typedef __bf16 bf16;
typedef __bf16 bf16x4 __attribute__((ext_vector_type(4)));
typedef __bf16 bf16x8 __attribute__((ext_vector_type(8)));
typedef float f32x4 __attribute__((ext_vector_type(4)));

#define BB 4
#define CC 512
#define NN 4096      // 64*64 spatial
#define NRR 1024     // 32*32 spatial (stride-2)
#define NHH 8
#define DKK 64

static __device__ __forceinline__ bf16x8 ld8(const bf16* p) {
    return *reinterpret_cast<const bf16x8*>(p);
}

// swizzled index: element (row, col) of a [rows x 64] stripe.
static __device__ __forceinline__ int swz(int row, int col) {
    return row * 64 + ((((col >> 3) ^ (row & 7)) << 3) | (col & 7));
}

// ---------------------------------------------------------------------------
// fused prep (layout A): blocks [0,4096) do weight permute/convert + stats
// zero; blocks [4096, 6144) do the x transpose.
// Wq is pre-scaled by 0.125*log2(e) so QK^T lands directly in exp2 domain.
// ---------------------------------------------------------------------------
static __device__ __forceinline__ void wprep_body(int e,
                                                  const float* __restrict__ Wq,
                                                  const float* __restrict__ Wp,
                                                  const float* __restrict__ Wk,
                                                  const float* __restrict__ Wv,
                                                  bf16* __restrict__ Wqb,
                                                  bf16* __restrict__ Wpb,
                                                  bf16* __restrict__ Wkf,
                                                  bf16* __restrict__ Wvf,
                                                  float* __restrict__ stats) {
    int o = e >> 11, q = (e >> 9) & 3, ci = e & 511;
    int src = o * 2048 + ci * 4 + q;
    Wkf[e] = (bf16)Wk[src];
    Wvf[e] = (bf16)Wv[src];
    if (e < 262144) {
        Wqb[e] = (bf16)(Wq[e] * 0.18033688011f);  // 0.125 * log2(e)
        Wpb[e] = (bf16)Wp[e];
    }
    if (e < 1024) stats[e] = 0.f;
}

__global__ __launch_bounds__(256) void prep_kernel(const float* __restrict__ Wq,
                                                   const float* __restrict__ Wp,
                                                   const float* __restrict__ Wk,
                                                   const float* __restrict__ Wv,
                                                   bf16* __restrict__ Wqb,
                                                   bf16* __restrict__ Wpb,
                                                   bf16* __restrict__ Wkf,
                                                   bf16* __restrict__ Wvf,
                                                   float* __restrict__ stats,
                                                   const float* __restrict__ x,
                                                   bf16* __restrict__ xt) {
    __shared__ bf16 tile[64][65];
    if (blockIdx.x < 4096) {
        int e = blockIdx.x * 256 + threadIdx.x;
        wprep_body(e, Wq, Wp, Wk, Wv, Wqb, Wpb, Wkf, Wvf, stats);
        return;
    }
    int bid = blockIdx.x - 4096;             // 2048 transpose blocks
    int b = bid >> 9;
    int by = (bid >> 6) & 7, bx = bid & 63;
    const float* xb = x + (size_t)b * CC * NN;
    bf16* xtb = xt + (size_t)b * NN * CC;
    int n0 = bx * 64, c0 = by * 64;
    int tr = threadIdx.x >> 6, tc = threadIdx.x & 63;
#pragma unroll
    for (int i = 0; i < 64; i += 4)
        tile[tc][i + tr] = (bf16)xb[(long)(c0 + i + tr) * NN + n0 + tc];
    __syncthreads();
#pragma unroll
    for (int i = 0; i < 64; i += 4)
        xtb[(long)(n0 + i + tr) * CC + c0 + tc] = tile[i + tr][tc];
}

// standalone versions for layout B (per-batch loop)
__global__ __launch_bounds__(256) void wprep_kernel(const float* __restrict__ Wq,
                                                    const float* __restrict__ Wp,
                                                    const float* __restrict__ Wk,
                                                    const float* __restrict__ Wv,
                                                    bf16* __restrict__ Wqb,
                                                    bf16* __restrict__ Wpb,
                                                    bf16* __restrict__ Wkf,
                                                    bf16* __restrict__ Wvf,
                                                    float* __restrict__ stats) {
    int e = blockIdx.x * 256 + threadIdx.x;
    wprep_body(e, Wq, Wp, Wk, Wv, Wqb, Wpb, Wkf, Wvf, stats);
}

__global__ __launch_bounds__(256) void transpose_kernel(const float* __restrict__ x,
                                                        bf16* __restrict__ xt) {
    __shared__ bf16 tile[64][65];
    int b = blockIdx.z;
    const float* xb = x + (size_t)b * CC * NN;
    bf16* xtb = xt + (size_t)b * NN * CC;
    int n0 = blockIdx.x * 64, c0 = blockIdx.y * 64;
    int tr = threadIdx.x >> 6, tc = threadIdx.x & 63;
#pragma unroll
    for (int i = 0; i < 64; i += 4)
        tile[tc][i + tr] = (bf16)xb[(long)(c0 + i + tr) * NN + n0 + tc];
    __syncthreads();
#pragma unroll
    for (int i = 0; i < 64; i += 4)
        xtb[(long)(n0 + i + tr) * CC + c0 + tc] = tile[i + tr][tc];
}

// ---------------------------------------------------------------------------
// Merged K+V GEMM, BK=64, 2-deep software pipeline (kept from R16: net win).
// ---------------------------------------------------------------------------
__global__ __launch_bounds__(256) void gemm_kv(const bf16* __restrict__ xt,
                                               const bf16* __restrict__ Wkf,
                                               const bf16* __restrict__ Wvf,
                                               bf16* __restrict__ kt,
                                               bf16* __restrict__ vt) {
    __shared__ __align__(16) bf16 smem[2][2][64][72];   // [dbuf][K/V][ch][k]
    const f32x4 fzero = {0.f, 0.f, 0.f, 0.f};
    int b = blockIdx.z;
    const bf16* xtb = xt + (size_t)b * NN * CC;
    int w = threadIdx.x >> 6, lane = threadIdx.x & 63;
    int quad = lane >> 4, l15 = lane & 15;
    int m0 = blockIdx.x * 64 + w * 16;
    int n0 = blockIdx.y * 64;

    int m = m0 + l15;
    int i2 = m >> 5, j2 = m & 31;
    int nrow[4];
#pragma unroll
    for (int q = 0; q < 4; ++q)
        nrow[q] = (2 * i2 + (q >> 1)) * 64 + 2 * j2 + (q & 1);

    int srow = threadIdx.x >> 2, sseg = threadIdx.x & 3;
    const bf16* wkp = Wkf + (long)(n0 + srow) * 2048 + sseg * 8;
    const bf16* wvp = Wvf + (long)(n0 + srow) * 2048 + sseg * 8;

    // prologue: stage tile 0 direct; hold tile 1 in regs; A for tiles 0,1
    {
        *reinterpret_cast<bf16x8*>(&smem[0][0][srow][sseg * 8]) = ld8(wkp);
        *reinterpret_cast<bf16x8*>(&smem[0][0][srow][32 + sseg * 8]) = ld8(wkp + 32);
        *reinterpret_cast<bf16x8*>(&smem[0][1][srow][sseg * 8]) = ld8(wvp);
        *reinterpret_cast<bf16x8*>(&smem[0][1][srow][32 + sseg * 8]) = ld8(wvp + 32);
    }
    bf16x8 svK0a = ld8(wkp + 64), svK1a = ld8(wkp + 96);
    bf16x8 svV0a = ld8(wvp + 64), svV1a = ld8(wvp + 96);
    bf16x8 aA0 = ld8(xtb + (long)nrow[0] * CC + quad * 8);
    bf16x8 aA1 = ld8(xtb + (long)nrow[0] * CC + 32 + quad * 8);
    bf16x8 aB0 = ld8(xtb + (long)nrow[0] * CC + 64 + quad * 8);
    bf16x8 aB1 = ld8(xtb + (long)nrow[0] * CC + 96 + quad * 8);
    __syncthreads();

    f32x4 accK[4], accV[4];
#pragma unroll
    for (int ct = 0; ct < 4; ++ct) { accK[ct] = fzero; accV[ct] = fzero; }

    bf16x8 svK0b, svK1b, svV0b, svV1b;
    for (int kp = 0; kp < 16; ++kp) {
        int s = 2 * kp;
        // ---- even step s: compute from smem[0] with aA
#pragma unroll
        for (int ct = 0; ct < 4; ++ct) {
            bf16x8 bk0 = ld8(&smem[0][0][ct * 16 + l15][quad * 8]);
            bf16x8 bv0 = ld8(&smem[0][1][ct * 16 + l15][quad * 8]);
            accK[ct] = __builtin_amdgcn_mfma_f32_16x16x32_bf16(aA0, bk0, accK[ct], 0, 0, 0);
            accV[ct] = __builtin_amdgcn_mfma_f32_16x16x32_bf16(aA0, bv0, accV[ct], 0, 0, 0);
            bf16x8 bk1 = ld8(&smem[0][0][ct * 16 + l15][32 + quad * 8]);
            bf16x8 bv1 = ld8(&smem[0][1][ct * 16 + l15][32 + quad * 8]);
            accK[ct] = __builtin_amdgcn_mfma_f32_16x16x32_bf16(aA1, bk1, accK[ct], 0, 0, 0);
            accV[ct] = __builtin_amdgcn_mfma_f32_16x16x32_bf16(aA1, bv1, accV[ct], 0, 0, 0);
        }
        // write held tile s+1 into smem[1]
        *reinterpret_cast<bf16x8*>(&smem[1][0][srow][sseg * 8]) = svK0a;
        *reinterpret_cast<bf16x8*>(&smem[1][0][srow][32 + sseg * 8]) = svK1a;
        *reinterpret_cast<bf16x8*>(&smem[1][1][srow][sseg * 8]) = svV0a;
        *reinterpret_cast<bf16x8*>(&smem[1][1][srow][32 + sseg * 8]) = svV1a;
        if (kp < 15) {
            int k2 = (s + 2) * 64;
            svK0b = ld8(wkp + k2); svK1b = ld8(wkp + k2 + 32);
            svV0b = ld8(wvp + k2); svV1b = ld8(wvp + k2 + 32);
            int q2 = k2 >> 9, ci2 = k2 & 511;
            aA0 = ld8(xtb + (long)nrow[q2] * CC + ci2 + quad * 8);
            aA1 = ld8(xtb + (long)nrow[q2] * CC + ci2 + 32 + quad * 8);
        }
        __syncthreads();
        // ---- odd step s+1: compute from smem[1] with aB
#pragma unroll
        for (int ct = 0; ct < 4; ++ct) {
            bf16x8 bk0 = ld8(&smem[1][0][ct * 16 + l15][quad * 8]);
            bf16x8 bv0 = ld8(&smem[1][1][ct * 16 + l15][quad * 8]);
            accK[ct] = __builtin_amdgcn_mfma_f32_16x16x32_bf16(aB0, bk0, accK[ct], 0, 0, 0);
            accV[ct] = __builtin_amdgcn_mfma_f32_16x16x32_bf16(aB0, bv0, accV[ct], 0, 0, 0);
            bf16x8 bk1 = ld8(&smem[1][0][ct * 16 + l15][32 + quad * 8]);
            bf16x8 bv1 = ld8(&smem[1][1][ct * 16 + l15][32 + quad * 8]);
            accK[ct] = __builtin_amdgcn_mfma_f32_16x16x32_bf16(aB1, bk1, accK[ct], 0, 0, 0);
            accV[ct] = __builtin_amdgcn_mfma_f32_16x16x32_bf16(aB1, bv1, accV[ct], 0, 0, 0);
        }
        if (kp < 15) {
            // write tile s+2 into smem[0]; load tile s+3 + its A
            *reinterpret_cast<bf16x8*>(&smem[0][0][srow][sseg * 8]) = svK0b;
            *reinterpret_cast<bf16x8*>(&smem[0][0][srow][32 + sseg * 8]) = svK1b;
            *reinterpret_cast<bf16x8*>(&smem[0][1][srow][sseg * 8]) = svV0b;
            *reinterpret_cast<bf16x8*>(&smem[0][1][srow][32 + sseg * 8]) = svV1b;
            int k3 = (s + 3) * 64;
            svK0a = ld8(wkp + k3); svK1a = ld8(wkp + k3 + 32);
            svV0a = ld8(wvp + k3); svV1a = ld8(wvp + k3 + 32);
            int q3 = k3 >> 9, ci3 = k3 & 511;
            aB0 = ld8(xtb + (long)nrow[q3] * CC + ci3 + quad * 8);
            aB1 = ld8(xtb + (long)nrow[q3] * CC + ci3 + 32 + quad * 8);
        }
        __syncthreads();
    }

    bf16* Ck = kt + (size_t)b * NRR * CC;
#pragma unroll
    for (int ct = 0; ct < 4; ++ct)
#pragma unroll
        for (int r = 0; r < 4; ++r)
            Ck[(long)(m0 + quad * 4 + r) * CC + n0 + ct * 16 + l15] = (bf16)accK[ct][r];

    bf16* tt = (bf16*)smem;   // viewed as [64][72]
#pragma unroll
    for (int ct = 0; ct < 4; ++ct)
#pragma unroll
        for (int r = 0; r < 4; ++r)
            tt[(ct * 16 + l15) * 72 + w * 16 + quad * 4 + r] = (bf16)accV[ct][r];
    __syncthreads();
    {
        int row = threadIdx.x >> 2, seg = threadIdx.x & 3;
        bf16x8 v0 = ld8(tt + row * 72 + seg * 16);
        bf16x8 v1 = ld8(tt + row * 72 + seg * 16 + 8);
        bf16* dst = vt + (size_t)b * CC * NRR + (long)(n0 + row) * NRR
                  + (long)blockIdx.x * 64 + seg * 16;
        *reinterpret_cast<bf16x8*>(dst) = v0;
        *reinterpret_cast<bf16x8*>(dst + 8) = v1;
    }
}

// ---------------------------------------------------------------------------
// flash attention, swapped-operand QK^T, FOUR query tiles per wave (64 q).
// m == 0 exact softmax. REVERTED to the R15 structure (83 us measured):
// single kf set + nf prefetch/copy, VGPR 120. R16's kfA/kfB alternation
// bloated VGPR to 188 and regressed 27%.
// ---------------------------------------------------------------------------
#define VST 64   // vbuf row stride (bf16 elements)
#define QT 4     // query tiles per wave
__global__ __launch_bounds__(256) void attn_kernel(const bf16* __restrict__ xt,
                                                   const bf16* __restrict__ Wqb,
                                                   const bf16* __restrict__ Kt,
                                                   const bf16* __restrict__ Vt,
                                                   const float* __restrict__ bias,
                                                   bf16* __restrict__ Ot) {
    __shared__ __align__(16) bf16 vbuf[2][64 * VST];    // [d][m] XOR-swizzled
    __shared__ __align__(16) bf16 ptile[4][64 * 64];    // per-wave swz stripes
    const f32x4 fzero = {0.f, 0.f, 0.f, 0.f};
    (void)bias;                                         // softmax-invariant
    int b = blockIdx.z, h = blockIdx.y;
    const bf16* xtb = xt + (size_t)b * NN * CC;
    const bf16* Ktb = Kt + (size_t)b * NRR * CC;
    const bf16* Vtb = Vt + (size_t)b * CC * NRR;        // [c][m] layout
    bf16* Otb = Ot + (size_t)b * NN * CC;
    int w = threadIdx.x >> 6, lane = threadIdx.x & 63;
    int quad = lane >> 4, l15 = lane & 15;
    int m0 = blockIdx.x * 256 + w * 64;                 // tiles at m0 + t*16

    // staging geometry: thread covers (d0, chunk) and (d0+32, chunk)
    int sd0 = threadIdx.x >> 3, schunk = threadIdx.x & 7;
    const bf16* vsrc0 = Vtb + (long)(h * DKK + sd0) * NRR + schunk * 8;
    const bf16* vsrc1 = vsrc0 + (long)32 * NRR;
    int soff0 = sd0 * VST + ((schunk ^ (sd0 & 7)) * 8);
    int soff1 = (sd0 + 32) * VST + ((schunk ^ (sd0 & 7)) * 8);

    // fused Q-GEMM for 4 tiles (Wq fragments shared)
    bf16* ql = &ptile[w][0];
    {
        f32x4 qacc[QT][4];
#pragma unroll
        for (int t = 0; t < QT; ++t)
#pragma unroll
            for (int ct = 0; ct < 4; ++ct) qacc[t][ct] = fzero;
        const bf16* axp = xtb + (long)(m0 + l15) * CC + quad * 8;
        const bf16* bwp = Wqb + (long)(h * DKK + l15) * CC + quad * 8;
        for (int k0 = 0; k0 < 512; k0 += 32) {
            bf16x8 av[QT];
#pragma unroll
            for (int t = 0; t < QT; ++t) av[t] = ld8(axp + t * 16 * CC + k0);
#pragma unroll
            for (int ct = 0; ct < 4; ++ct) {
                bf16x8 bv = ld8(bwp + k0 + ct * 16 * CC);
#pragma unroll
                for (int t = 0; t < QT; ++t)
                    qacc[t][ct] = __builtin_amdgcn_mfma_f32_16x16x32_bf16(av[t], bv, qacc[t][ct], 0, 0, 0);
            }
        }
#pragma unroll
        for (int t = 0; t < QT; ++t)
#pragma unroll
            for (int ct = 0; ct < 4; ++ct)
#pragma unroll
                for (int r = 0; r < 4; ++r)
                    ql[swz(t * 16 + quad * 4 + r, ct * 16 + l15)] = (bf16)qacc[t][ct][r];
    }
    asm volatile("s_waitcnt lgkmcnt(0)" ::: "memory");
    __builtin_amdgcn_sched_barrier(0);
    bf16x8 aq0[QT], aq1[QT];
#pragma unroll
    for (int t = 0; t < QT; ++t) {
        aq0[t] = ld8(ql + swz(t * 16 + l15, quad * 8));
        aq1[t] = ld8(ql + swz(t * 16 + l15, 32 + quad * 8));
    }

    // prologue: stage V tile 0; preload K fragments for tile 0
    {
        bf16x8 s0 = ld8(vsrc0);
        bf16x8 s1 = ld8(vsrc1);
        *reinterpret_cast<bf16x8*>(&vbuf[0][0] + soff0) = s0;
        *reinterpret_cast<bf16x8*>(&vbuf[0][0] + soff1) = s1;
    }
    const bf16* kbase = Ktb + (long)l15 * CC + h * DKK + quad * 8;
    bf16x8 kf0[4], kf1[4];
#pragma unroll
    for (int ct = 0; ct < 4; ++ct) {
        kf0[ct] = ld8(kbase + (long)ct * 16 * CC);
        kf1[ct] = ld8(kbase + (long)ct * 16 * CC + 32);
    }
    __syncthreads();

    f32x4 oacc[QT][4];
    float lrow[QT];
#pragma unroll
    for (int t = 0; t < QT; ++t) {
        lrow[t] = 0.f;
#pragma unroll
        for (int ct = 0; ct < 4; ++ct) oacc[t][ct] = fzero;
    }

    for (int kt = 0; kt < 16; ++kt) {
        int cur = kt & 1;
        bf16x8 sv0, sv1;
        if (kt < 15) {
            sv0 = ld8(vsrc0 + (kt + 1) * 64);
            sv1 = ld8(vsrc1 + (kt + 1) * 64);
        }

        // per tile: QK^T (K fragments shared) -> P = exp2(s) -> P write
        bf16* pl = &ptile[w][0];
#pragma unroll
        for (int t = 0; t < QT; ++t) {
            f32x4 s[4];
#pragma unroll
            for (int ct = 0; ct < 4; ++ct) s[ct] = fzero;
            __builtin_amdgcn_s_setprio(1);
#pragma unroll
            for (int ct = 0; ct < 4; ++ct) {
                s[ct] = __builtin_amdgcn_mfma_f32_16x16x32_bf16(kf0[ct], aq0[t], s[ct], 0, 0, 0);
                s[ct] = __builtin_amdgcn_mfma_f32_16x16x32_bf16(kf1[ct], aq1[t], s[ct], 0, 0, 0);
            }
            __builtin_amdgcn_s_setprio(0);
            float ls = 0.f;
#pragma unroll
            for (int ct = 0; ct < 4; ++ct) {
                bf16x4 pk;
#pragma unroll
                for (int r = 0; r < 4; ++r) {
                    float e = __builtin_amdgcn_exp2f(s[ct][r]);
                    ls += e;
                    pk[r] = (bf16)e;
                }
                *reinterpret_cast<bf16x4*>(pl + swz(t * 16 + l15, ct * 16 + quad * 4)) = pk;
            }
            lrow[t] += ls;
        }
        asm volatile("s_waitcnt lgkmcnt(0)" ::: "memory");
        __builtin_amdgcn_sched_barrier(0);

        // ---- issue next-tile K loads here (hidden under PV + barrier)
        bf16x8 nf0[4], nf1[4];
        if (kt < 15) {
            const bf16* kn = kbase + (long)(kt + 1) * 64 * CC;
#pragma unroll
            for (int ct = 0; ct < 4; ++ct) {
                nf0[ct] = ld8(kn + (long)ct * 16 * CC);
                nf1[ct] = ld8(kn + (long)ct * 16 * CC + 32);
            }
        }

        // O^T += V^T P^T  (V fragments shared across 4 tiles)
        const bf16* vb = &vbuf[cur][0];
        __builtin_amdgcn_s_setprio(1);
#pragma unroll
        for (int ks = 0; ks < 2; ++ks) {
            bf16x8 bp[QT];
#pragma unroll
            for (int t = 0; t < QT; ++t)
                bp[t] = ld8(pl + swz(t * 16 + l15, ks * 32 + quad * 8));
#pragma unroll
            for (int ct = 0; ct < 4; ++ct) {
                int d = ct * 16 + l15;
                bf16x8 av = ld8(vb + d * VST + (((ks * 4 + quad) ^ (d & 7)) * 8));
#pragma unroll
                for (int t = 0; t < QT; ++t)
                    oacc[t][ct] = __builtin_amdgcn_mfma_f32_16x16x32_bf16(av, bp[t], oacc[t][ct], 0, 0, 0);
            }
        }
        __builtin_amdgcn_s_setprio(0);

        if (kt < 15) {
            bf16* wb = &vbuf[cur ^ 1][0];
            *reinterpret_cast<bf16x8*>(wb + soff0) = sv0;
            *reinterpret_cast<bf16x8*>(wb + soff1) = sv1;
#pragma unroll
            for (int ct = 0; ct < 4; ++ct) { kf0[ct] = nf0[ct]; kf1[ct] = nf1[ct]; }
        }
        __syncthreads();
    }

    // final denominators + O epilogue per tile
    bf16* pl = &ptile[w][0];
#pragma unroll
    for (int t = 0; t < QT; ++t) {
        float lr = lrow[t];
        lr += __shfl_xor(lr, 16);
        lr += __shfl_xor(lr, 32);
        float inv = 1.f / lr;
#pragma unroll
        for (int ct = 0; ct < 4; ++ct) {
            bf16x4 ok;
#pragma unroll
            for (int r = 0; r < 4; ++r) ok[r] = (bf16)(oacc[t][ct][r] * inv);
            *reinterpret_cast<bf16x4*>(pl + swz(t * 16 + l15, ct * 16 + quad * 4)) = ok;
        }
    }
    asm volatile("s_waitcnt lgkmcnt(0)" ::: "memory");
    __builtin_amdgcn_sched_barrier(0);
#pragma unroll
    for (int t = 0; t < QT; ++t) {
        bf16x8 o0 = ld8(pl + swz(t * 16 + l15, quad * 16));
        bf16x8 o1 = ld8(pl + swz(t * 16 + l15, quad * 16 + 8));
        bf16* dst = Otb + (long)(m0 + t * 16 + l15) * CC + h * DKK + quad * 16;
        *reinterpret_cast<bf16x8*>(dst) = o0;
        *reinterpret_cast<bf16x8*>(dst + 8) = o1;
    }
}

// ---------------------------------------------------------------------------
// proj: p[b,o,n] = Wproj . ot[b,n,:]^T, fp32 out; LDS-staged GEMM, BK=64,
// 2-deep pipeline (kept from R16). BN stats fused.
// ---------------------------------------------------------------------------
__global__ __launch_bounds__(256) void gemm_ntf(const bf16* __restrict__ A,
                                                const bf16* __restrict__ Bt,
                                                float* __restrict__ C,
                                                float* __restrict__ stats) {
    __shared__ __align__(16) bf16 sa[2][64][72];   // Wpb tile [ch][k]
    __shared__ __align__(16) bf16 sb[2][64][72];   // ot tile [px][k]
    const f32x4 fzero = {0.f, 0.f, 0.f, 0.f};
    int b = blockIdx.z;
    const bf16* Btb = Bt + (size_t)b * NN * CC;
    float* Cb = C + (size_t)b * CC * NN;
    int w = threadIdx.x >> 6, lane = threadIdx.x & 63;
    int quad = lane >> 4, l15 = lane & 15;
    long m0 = (long)blockIdx.x * 64 + w * 16;
    long n0 = (long)blockIdx.y * 64;

    int srow = threadIdx.x >> 2, sseg = threadIdx.x & 3;
    const bf16* apS = A + ((long)blockIdx.x * 64 + srow) * CC + sseg * 8;
    const bf16* bpS = Btb + (n0 + srow) * CC + sseg * 8;

    // prologue: tile 0 direct; tile 1 held in set A
    {
        *reinterpret_cast<bf16x8*>(&sa[0][srow][sseg * 8]) = ld8(apS);
        *reinterpret_cast<bf16x8*>(&sa[0][srow][32 + sseg * 8]) = ld8(apS + 32);
        *reinterpret_cast<bf16x8*>(&sb[0][srow][sseg * 8]) = ld8(bpS);
        *reinterpret_cast<bf16x8*>(&sb[0][srow][32 + sseg * 8]) = ld8(bpS + 32);
    }
    bf16x8 svA0a = ld8(apS + 64), svA1a = ld8(apS + 96);
    bf16x8 svB0a = ld8(bpS + 64), svB1a = ld8(bpS + 96);
    __syncthreads();

    f32x4 acc[4];
#pragma unroll
    for (int ct = 0; ct < 4; ++ct) acc[ct] = fzero;

    bf16x8 svA0b, svA1b, svB0b, svB1b;
    for (int kp = 0; kp < 4; ++kp) {
        int s = 2 * kp;
        // even step: compute from [0]
        {
            bf16x8 a0 = ld8(&sa[0][w * 16 + l15][quad * 8]);
            bf16x8 a1 = ld8(&sa[0][w * 16 + l15][32 + quad * 8]);
#pragma unroll
            for (int ct = 0; ct < 4; ++ct) {
                bf16x8 b0 = ld8(&sb[0][ct * 16 + l15][quad * 8]);
                acc[ct] = __builtin_amdgcn_mfma_f32_16x16x32_bf16(a0, b0, acc[ct], 0, 0, 0);
                bf16x8 b1 = ld8(&sb[0][ct * 16 + l15][32 + quad * 8]);
                acc[ct] = __builtin_amdgcn_mfma_f32_16x16x32_bf16(a1, b1, acc[ct], 0, 0, 0);
            }
        }
        *reinterpret_cast<bf16x8*>(&sa[1][srow][sseg * 8]) = svA0a;
        *reinterpret_cast<bf16x8*>(&sa[1][srow][32 + sseg * 8]) = svA1a;
        *reinterpret_cast<bf16x8*>(&sb[1][srow][sseg * 8]) = svB0a;
        *reinterpret_cast<bf16x8*>(&sb[1][srow][32 + sseg * 8]) = svB1a;
        if (kp < 3) {
            int k2 = (s + 2) * 64;
            svA0b = ld8(apS + k2); svA1b = ld8(apS + k2 + 32);
            svB0b = ld8(bpS + k2); svB1b = ld8(bpS + k2 + 32);
        }
        __syncthreads();
        // odd step: compute from [1]
        {
            bf16x8 a0 = ld8(&sa[1][w * 16 + l15][quad * 8]);
            bf16x8 a1 = ld8(&sa[1][w * 16 + l15][32 + quad * 8]);
#pragma unroll
            for (int ct = 0; ct < 4; ++ct) {
                bf16x8 b0 = ld8(&sb[1][ct * 16 + l15][quad * 8]);
                acc[ct] = __builtin_amdgcn_mfma_f32_16x16x32_bf16(a0, b0, acc[ct], 0, 0, 0);
                bf16x8 b1 = ld8(&sb[1][ct * 16 + l15][32 + quad * 8]);
                acc[ct] = __builtin_amdgcn_mfma_f32_16x16x32_bf16(a1, b1, acc[ct], 0, 0, 0);
            }
        }
        if (kp < 3) {
            *reinterpret_cast<bf16x8*>(&sa[0][srow][sseg * 8]) = svA0b;
            *reinterpret_cast<bf16x8*>(&sa[0][srow][32 + sseg * 8]) = svA1b;
            *reinterpret_cast<bf16x8*>(&sb[0][srow][sseg * 8]) = svB0b;
            *reinterpret_cast<bf16x8*>(&sb[0][srow][32 + sseg * 8]) = svB1b;
            int k3 = (s + 3) * 64;
            svA0a = ld8(apS + k3); svA1a = ld8(apS + k3 + 32);
            svB0a = ld8(bpS + k3); svB1a = ld8(bpS + k3 + 32);
        }
        __syncthreads();
    }

    float ps[4], pss[4];
#pragma unroll
    for (int r = 0; r < 4; ++r) { ps[r] = 0.f; pss[r] = 0.f; }
#pragma unroll
    for (int ct = 0; ct < 4; ++ct)
#pragma unroll
        for (int r = 0; r < 4; ++r) {
            float v = acc[ct][r];
            Cb[(m0 + quad * 4 + r) * NN + n0 + ct * 16 + l15] = v;
            ps[r] += v; pss[r] += v * v;
        }
#pragma unroll
    for (int off = 1; off < 16; off <<= 1)
#pragma unroll
        for (int r = 0; r < 4; ++r) {
            ps[r] += __shfl_xor(ps[r], off);
            pss[r] += __shfl_xor(pss[r], off);
        }
    if (l15 == 0) {
#pragma unroll
        for (int r = 0; r < 4; ++r) {
            int c = (int)(m0 + quad * 4 + r);
            atomicAdd(&stats[c * 2], ps[r]);
            atomicAdd(&stats[c * 2 + 1], pss[r]);
        }
    }
}

// ---------------------------------------------------------------------------
// y = x + bn(p); LayerNorm over C per pixel. Single global read pass:
// y cached in LDS (512ch x 32px fp32 = 64 KB), second pass reads LDS only.
// ---------------------------------------------------------------------------
__global__ __launch_bounds__(256) void final_kernel(const float* __restrict__ x,
                                                    const float* __restrict__ p,
                                                    const float* __restrict__ stats,
                                                    const float* __restrict__ bng,
                                                    const float* __restrict__ bnb,
                                                    const float* __restrict__ lg,
                                                    const float* __restrict__ lb,
                                                    float* __restrict__ out) {
    __shared__ float yt[512 * 32];           // [c][px], stride 32 (2-way, free)
    __shared__ float scs[512], shs[512], lgs[512], lbs[512];
    __shared__ float rs[8][32], rss[8][32];
    for (int c = threadIdx.x; c < 512; c += 256) {
        float sum = stats[c * 2], ssq = stats[c * 2 + 1];
        float mean = sum * (1.f / 16384.f);
        float var = ssq * (1.f / 16384.f) - mean * mean;
        float rstd = rsqrtf(var + 1e-5f);
        float sc = bng[c] * rstd;
        scs[c] = sc;
        shs[c] = bnb[c] - mean * sc;
        lgs[c] = lg[c];
        lbs[c] = lb[c];
    }
    __syncthreads();
    int blk = blockIdx.x;
    int b = blk >> 7;                        // 128 pixel-groups per batch
    int pix0 = (blk & 127) * 32;
    int sub = threadIdx.x >> 5, px = threadIdx.x & 31;   // 8 subs x 32 px
    float s = 0.f, ss = 0.f;
    for (int i = 0; i < 64; ++i) {
        int c = i * 8 + sub;
        long idx = ((long)(b * CC + c)) * NN + pix0 + px;
        float y = x[idx] + p[idx] * scs[c] + shs[c];
        yt[c * 32 + px] = y;
        s += y; ss += y * y;
    }
    rs[sub][px] = s; rss[sub][px] = ss;
    __syncthreads();
    float sum = 0.f, sq = 0.f;
#pragma unroll
    for (int j = 0; j < 8; ++j) { sum += rs[j][px]; sq += rss[j][px]; }
    float mu = sum * (1.f / 512.f);
    float var = sq * (1.f / 512.f) - mu * mu;
    float rstd = rsqrtf(var + 1e-5f);
    for (int i = 0; i < 64; ++i) {
        int c = i * 8 + sub;
        long idx = ((long)(b * CC + c)) * NN + pix0 + px;
        out[idx] = (yt[c * 32 + px] - mu) * rstd * lgs[c] + lbs[c];
    }
}

// ---------------------------------------------------------------------------
extern "C" void kernel_launch(void* const* d_in, const int* in_sizes, int n_in,
                              void* d_out, int out_size, void* d_ws, size_t ws_size,
                              hipStream_t stream) {
    (void)in_sizes; (void)n_in; (void)out_size;
    const float* x     = (const float*)d_in[0];
    const float* Wq    = (const float*)d_in[1];
    const float* Wk    = (const float*)d_in[2];
    const float* Wv    = (const float*)d_in[3];
    const float* bias  = (const float*)d_in[4];
    const float* Wproj = (const float*)d_in[5];
    const float* bng   = (const float*)d_in[6];
    const float* bnb   = (const float*)d_in[7];
    const float* lng   = (const float*)d_in[8];
    const float* lnb   = (const float*)d_in[9];
    float* out = (float*)d_out;   // fp32 output (verified R9)

    char* ws = (char*)d_ws;
    size_t off = 0;
    auto alloc = [&](size_t bytes) {
        char* pp = ws + off;
        off += (bytes + 255) & ~(size_t)255;
        return pp;
    };
    bf16* Wqb = (bf16*)alloc((size_t)CC * CC * 2);          // 0.52 MB
    bf16* Wpb = (bf16*)alloc((size_t)CC * CC * 2);          // 0.52 MB
    float* stats = (float*)alloc(512 * 2 * sizeof(float));

    size_t needA = off + ((size_t)CC * 2048 * 2 * 2)        // Wkf+Wvf 4.2 MB
                 + ((size_t)BB * NN * CC * 2)               // xt_all 16.8
                 + ((size_t)BB * NRR * CC * 2 * 2)          // kt+vt   8.4
                 + ((size_t)BB * NN * CC * 2) + 4096;       // ot_all 16.8

    if (ws_size >= needA) {
        bf16* Wkf = (bf16*)alloc((size_t)CC * 2048 * 2);
        bf16* Wvf = (bf16*)alloc((size_t)CC * 2048 * 2);
        bf16* xt  = (bf16*)alloc((size_t)BB * NN * CC * 2);
        bf16* kt  = (bf16*)alloc((size_t)BB * NRR * CC * 2);
        bf16* vt  = (bf16*)alloc((size_t)BB * NRR * CC * 2);   // holds V^T [c][m]
        bf16* ot  = (bf16*)alloc((size_t)BB * NN * CC * 2);

        prep_kernel<<<4096 + 2048, 256, 0, stream>>>(Wq, Wproj, Wk, Wv, Wqb, Wpb,
                                                     Wkf, Wvf, stats, x, xt);
        gemm_kv<<<dim3(16, 8, BB), 256, 0, stream>>>(xt, Wkf, Wvf, kt, vt);
        attn_kernel<<<dim3(16, NHH, BB), 256, 0, stream>>>(xt, Wqb, kt, vt, bias, ot);
        gemm_ntf<<<dim3(8, 64, BB), 256, 0, stream>>>(Wpb, ot, out, stats);
    } else {
        bf16* Wkf = (bf16*)(out + (size_t)3 * CC * NN);
        bf16* Wvf = Wkf + (size_t)CC * 2048;
        bf16* xt = (bf16*)alloc((size_t)NN * CC * 2);
        bf16* kt = (bf16*)alloc((size_t)NRR * CC * 2);
        bf16* vt = (bf16*)alloc((size_t)NRR * CC * 2);         // V^T [c][m]
        bf16* ot = (bf16*)alloc((size_t)NN * CC * 2);

        wprep_kernel<<<4096, 256, 0, stream>>>(Wq, Wproj, Wk, Wv, Wqb, Wpb, Wkf, Wvf, stats);
        for (int b = 0; b < BB; ++b) {
            const float* xb = x + (size_t)b * CC * NN;
            float* pb = out + (size_t)b * CC * NN;
            transpose_kernel<<<dim3(64, 8, 1), 256, 0, stream>>>(xb, xt);
            gemm_kv<<<dim3(16, 8, 1), 256, 0, stream>>>(xt, Wkf, Wvf, kt, vt);
            attn_kernel<<<dim3(16, NHH, 1), 256, 0, stream>>>(xt, Wqb, kt, vt, bias, ot);
            gemm_ntf<<<dim3(8, 64, 1), 256, 0, stream>>>(Wpb, ot, pb, stats);
        }
    }

    final_kernel<<<512, 256, 0, stream>>>(x, out, stats, bng, bnb, lng, lnb, out);
}